// Round 7
// baseline (27.808 us; speedup 1.0000x reference)
//
#include <hip/hip_runtime.h>

// CASSI base-mode forward on MI355X (gfx950).
// x:  (1, 31, 1024, 1024) f32, ca: (1, 1, 1024, 1024) f32
// out: (1, 1, 1024, 1054) f32
// Gather: out[m][c] = sum_l x[l][m][c-l] * ca[m][c-l].
//
// Round-7: scheduling restructure. R6's 5x1024 grid wasted ~20% of block
// slots (the 5th col-tile per row has 30/256 real columns but full latency-
// bound duration) and ran 2.5 resident rounds (last one half-occupied).
// Now: 2048 main blocks (1 row x 512 cols, 2 outputs/thread, one 542-float
// ca stage, one barrier, 62 loads) = exactly ONE balanced resident round at
// 8 blocks/CU (32 waves/CU, launch_bounds(256,8)); plus 128 mini tail blocks
// (8 rows x 30 cols, ~1/8 work, direct ca reads) dispatched FIRST so the 128
// leftover mains backfill their slots. XCD-chunked swizzle on main tiles
// (block i -> XCD i%8; 128 % 8 == 0 keeps phase).

constexpr int L = 31;
constexpr int M = 1024;
constexpr int N = 1024;
constexpr int NC = N + L - 1;            // 1054 output columns
constexpr int LSTRIDE = M * N;
constexpr int BLK = 256;
constexpr int HALO = L - 1;              // 30
constexpr int W = 512;                   // main-block column span
constexpr int CA_TILE = W + HALO;        // 542 staged ca columns
constexpr int NMINI = 128;               // tail blocks (8 rows x 30 cols each)
constexpr int NMAIN = 2 * M;             // 2048 main blocks

__global__ __launch_bounds__(BLK, 8) void cassi_fwd_kernel(
    const float* __restrict__ x,
    const float* __restrict__ ca,
    float* __restrict__ out)
{
    const int i = blockIdx.x;
    const int t = threadIdx.x;

    if (i < NMINI) {
        // Tail: output cols 1024..1053, rows 8i..8i+7. 240 active threads.
        if (t < 240) {
            const int r = t / 30;
            const int c = N + (t - 30 * r);       // 1024..1053
            const int m = 8 * i + r;
            const int llo = c - (N - 1);          // 1..30
            float a = 0.0f;
            for (int l = llo; l < L; ++l) {
                const int col = c - l;            // 994..1023, in-bounds
                a = fmaf(x[(long)l * LSTRIDE + m * N + col],
                         ca[m * N + col], a);
            }
            out[m * NC + c] = a;
        }
        return;
    }

    // Main: one row, 512 columns, 2 outputs per thread.
    const int j  = i - NMINI;
    const int jj = (j & 7) * (NMAIN / 8) + (j >> 3);   // XCD-chunked, bijective
    const int m  = jj >> 1;
    const int C0 = (jj & 1) * W;

    __shared__ float sca[CA_TILE];
    for (int k = t; k < CA_TILE; k += BLK) {
        const int col = C0 - HALO + k;
        sca[k] = ((unsigned)col < (unsigned)N) ? ca[m * N + col] : 0.0f;
    }
    __syncthreads();

    // x offsets proven in-bounds: max (l=30,m=1023,c=1023) = 31*2^20-31-...,
    // < 31*2^20; min (l>=1, c<l) >= 2^20-30 > 0 (garbage * 0.0 from pad).
    const float* xp = x + m * N + C0 + t;
    float a0 = 0.0f, a1 = 0.0f;
#pragma unroll
    for (int l = 0; l < L; ++l) {
        const long o = (long)l * LSTRIDE - l;
        a0 = fmaf(xp[o],       sca[t + HALO - l],       a0);
        a1 = fmaf(xp[o + 256], sca[t + 256 + HALO - l], a1);
    }

    float* op = out + m * NC + C0 + t;
    op[0]   = a0;
    op[256] = a1;
}

extern "C" void kernel_launch(void* const* d_in, const int* in_sizes, int n_in,
                              void* d_out, int out_size, void* d_ws, size_t ws_size,
                              hipStream_t stream)
{
    const float* x  = (const float*)d_in[0];
    const float* ca = (const float*)d_in[1];
    float* out = (float*)d_out;

    dim3 block(BLK, 1, 1);
    dim3 grid(NMINI + NMAIN, 1, 1);       // 2176 blocks; minis first
    cassi_fwd_kernel<<<grid, block, 0, stream>>>(x, ca, out);
}